// Round 2
// baseline (1322.811 us; speedup 1.0000x reference)
//
#include <hip/hip_runtime.h>
#include <math.h>

#define B_   64
#define T_   500
#define IN_  1024
#define G_   8
#define HG_  128
#define J3_  384   // 3*HG

// ---------------------------------------------------------------------------
// Kernel A: input projection GEMM (fp32 vector, 8x8 register micro-tile)
//   xp[(tau*64 + b)*G + g][j] = sum_i x[b, t0+tau, g*128+i] * W_ih[g][j][i] + b_ih[g][j]
// ---------------------------------------------------------------------------
__global__ __launch_bounds__(256, 3)
void gru_xproj(const float* __restrict__ x, const float* __restrict__ Wih,
               const float* __restrict__ bih, float* __restrict__ xp,
               int t0)
{
    __shared__ float xs[128 * 32];
    __shared__ float wsm[128 * 32];

    const int tid = threadIdx.x;
    const int tx = tid & 15;        // j micro index
    const int ty = tid >> 4;        // row micro index
    const int g  = blockIdx.z;
    const int j0 = blockIdx.y * 128;
    const int row0 = blockIdx.x * 128;   // row id = tau*64 + b (within chunk)

    float acc[8][8];
#pragma unroll
    for (int m = 0; m < 8; ++m)
#pragma unroll
        for (int n = 0; n < 8; ++n) acc[m][n] = 0.f;

    for (int kc = 0; kc < 4; ++kc) {
        __syncthreads();   // protect previous iteration's LDS reads
#pragma unroll
        for (int q = 0; q < 4; ++q) {
            const int f  = tid + 256 * q;   // 0..1023
            const int r  = f >> 3;
            const int k4 = f & 7;
            const int rowid = row0 + r;
            const int b   = rowid & 63;
            const int tau = rowid >> 6;
            const float4 xv = *(const float4*)(x + (size_t)(b * T_ + t0 + tau) * IN_
                                                 + g * HG_ + kc * 32 + k4 * 4);
            *(float4*)(xs + r * 32 + ((k4 ^ (r & 7)) << 2)) = xv;
            const float4 wv = *(const float4*)(Wih + (size_t)(g * J3_ + j0 + r) * HG_
                                                   + kc * 32 + k4 * 4);
            *(float4*)(wsm + r * 32 + ((k4 ^ (r & 7)) << 2)) = wv;
        }
        __syncthreads();

#pragma unroll
        for (int k4 = 0; k4 < 8; ++k4) {
            float4 xv[8], wv[8];
#pragma unroll
            for (int m = 0; m < 8; ++m) {
                const int r = ty + 16 * m;
                xv[m] = *(const float4*)(xs + r * 32 + ((k4 ^ (r & 7)) << 2));
            }
#pragma unroll
            for (int n = 0; n < 8; ++n) {
                const int r = tx + 16 * n;
                wv[n] = *(const float4*)(wsm + r * 32 + ((k4 ^ (r & 7)) << 2));
            }
#pragma unroll
            for (int m = 0; m < 8; ++m)
#pragma unroll
                for (int n = 0; n < 8; ++n) {
                    acc[m][n] += xv[m].x * wv[n].x;
                    acc[m][n] += xv[m].y * wv[n].y;
                    acc[m][n] += xv[m].z * wv[n].z;
                    acc[m][n] += xv[m].w * wv[n].w;
                }
        }
    }

#pragma unroll
    for (int m = 0; m < 8; ++m) {
        const int rowid = row0 + ty + 16 * m;
        float* dst = xp + ((size_t)rowid * G_ + g) * J3_ + j0;
#pragma unroll
        for (int n = 0; n < 8; ++n) {
            const int j = tx + 16 * n;
            dst[j] = acc[m][n] + bih[g * J3_ + j0 + j];
        }
    }
}

// ---------------------------------------------------------------------------
// Kernel B (structure C): one WG = 384 threads per (b,g) sequence.
// Thread j (0..383) holds the FULL row W_hh[g][j][0:128] in 128 VGPRs and
// computes its complete dot product against h broadcast from LDS (uniform
// ds_read_b128 = conflict-free broadcast). No partial reduce. Per step:
//   all: 32x{b128 bcast read + 4 FMA} -> hp_lds[j] -> barrier
//   p==0 (2 waves): gates from hp_lds + prefetched x -> h_lds + out -> barrier
// xp loads double-buffered in registers (issued one full step early).
// ---------------------------------------------------------------------------
__global__ __launch_bounds__(384, 3)
void gru_rec(const float* __restrict__ Whh, const float* __restrict__ bhh,
             const float* __restrict__ xp, float* __restrict__ out,
             float* __restrict__ hstate, int t0, int tc)
{
    const int tid = threadIdx.x;     // j = tid in [0,384)
    const int blk = blockIdx.x;      // 0..511
    const int b   = blk >> 3;
    const int g   = blk & 7;

    __shared__ float h_lds[HG_];
    __shared__ float hp_lds[J3_];

    // full W row into registers (32 float4 = 128 VGPR)
    float4 w[32];
    {
        const float* wr = Whh + (size_t)(g * J3_ + tid) * HG_;
#pragma unroll
        for (int i = 0; i < 32; ++i) w[i] = ((const float4*)wr)[i];
    }
    const float bias = bhh[g * J3_ + tid];

    const int p  = tid >> 7;         // gate id 0..2 (wave-uniform)
    const int jq = tid & 127;

    float hreg = 0.f;
    if (p == 0) {
        hreg = (t0 == 0) ? 0.f : hstate[(b * G_ + g) * HG_ + jq];
        h_lds[jq] = hreg;
    }
    __syncthreads();

    const float*  xpb     = xp + ((size_t)b * G_ + g) * J3_;
    const size_t  tstride = (size_t)B_ * G_ * J3_;
    float* outb = out + (size_t)b * T_ * IN_ + (size_t)t0 * IN_ + g * HG_;

    // prefetch x for tau=0
    float xr = 0.f, xz = 0.f, xn = 0.f;
    if (p == 0) {
        xr = xpb[jq]; xz = xpb[128 + jq]; xn = xpb[256 + jq];
    }

    for (int tau = 0; tau < tc; ++tau) {
        // issue next step's x loads (hidden under this step's FMA + gates)
        float nxr = 0.f, nxz = 0.f, nxn = 0.f;
        if (p == 0) {
            const int tn = (tau + 1 < tc) ? tau + 1 : tau;
            const float* xpt = xpb + (size_t)tn * tstride;
            nxr = xpt[jq]; nxz = xpt[128 + jq]; nxn = xpt[256 + jq];
        }

        // full dot: h broadcast from LDS, weights in registers
        float acc = 0.f;
#pragma unroll
        for (int i = 0; i < 32; ++i) {
            const float4 hv = ((const float4*)h_lds)[i];
            acc += w[i].x * hv.x;
            acc += w[i].y * hv.y;
            acc += w[i].z * hv.z;
            acc += w[i].w * hv.w;
        }
        hp_lds[tid] = acc + bias;
        __syncthreads();

        if (p == 0) {
            const float hr = hp_lds[jq];
            const float hz = hp_lds[128 + jq];
            const float hn = hp_lds[256 + jq];
            const float r = 1.f / (1.f + __expf(-(xr + hr)));
            const float z = 1.f / (1.f + __expf(-(xz + hz)));
            const float pre = xn + r * hn;
            const float e2  = __expf(-2.f * fabsf(pre));
            float th = (1.f - e2) / (1.f + e2);
            th = copysignf(th, pre);
            const float hnew = (1.f - z) * th + z * hreg;
            hreg = hnew;
            h_lds[jq] = hnew;
            outb[(size_t)tau * IN_ + jq] = hnew;
        }
        __syncthreads();

        xr = nxr; xz = nxz; xn = nxn;
    }

    if (p == 0) hstate[(b * G_ + g) * HG_ + jq] = hreg;
}

// ---------------------------------------------------------------------------
extern "C" void kernel_launch(void* const* d_in, const int* in_sizes, int n_in,
                              void* d_out, int out_size, void* d_ws, size_t ws_size,
                              hipStream_t stream) {
    (void)in_sizes; (void)n_in; (void)out_size;
    const float* x   = (const float*)d_in[0];
    const float* Wih = (const float*)d_in[1];
    const float* Whh = (const float*)d_in[2];
    const float* bih = (const float*)d_in[3];
    const float* bhh = (const float*)d_in[4];
    float* out = (float*)d_out;

    // ws layout: [h-state: B*G*128 floats = 256KB][xp chunk buffer]
    const size_t hBytes = (size_t)B_ * G_ * HG_ * sizeof(float);   // 262144
    float* hstate = (float*)d_ws;
    float* xpbuf  = (float*)((char*)d_ws + hBytes);

    const size_t perT  = (size_t)B_ * G_ * J3_ * sizeof(float);    // 786432 B per timestep
    const size_t avail = (ws_size > hBytes) ? (ws_size - hBytes) : 0;

    // even divisors of 500, largest chunk that fits in ws
    const int cands[8] = {500, 250, 100, 50, 20, 10, 4, 2};
    int tc = 2;
    for (int i = 0; i < 8; ++i) {
        if ((size_t)cands[i] * perT <= avail) { tc = cands[i]; break; }
    }

    for (int t0 = 0; t0 < T_; t0 += tc) {
        dim3 gA(tc * 64 / 128, J3_ / 128, G_);   // (tc/2, 3, 8)
        gru_xproj<<<gA, 256, 0, stream>>>(x, Wih, bih, xpbuf, t0);
        gru_rec<<<512, 384, 0, stream>>>(Whh, bhh, xpbuf, out, hstate, t0, tc);
    }
}

// Round 3
// 846.696 us; speedup vs baseline: 1.5623x; 1.5623x over previous
//
#include <hip/hip_runtime.h>
#include <math.h>

#define B_   64
#define T_   500
#define IN_  1024
#define G_   8
#define HG_  128
#define J3_  384   // 3*HG

typedef _Float16 half8 __attribute__((ext_vector_type(8)));
typedef float    f32x4 __attribute__((ext_vector_type(4)));

// ---------------------------------------------------------------------------
// Kernel A: input projection GEMM (fp32 vector, 8x8 register micro-tile)
//   xp[(tau*64 + b)*G + g][j] = sum_i x[b, t0+tau, g*128+i] * W_ih[g][j][i] + b_ih[g][j]
// (unchanged from round 1 — known good, ~330 us; MFMA conversion is next)
// ---------------------------------------------------------------------------
__global__ __launch_bounds__(256, 3)
void gru_xproj(const float* __restrict__ x, const float* __restrict__ Wih,
               const float* __restrict__ bih, float* __restrict__ xp,
               int t0)
{
    __shared__ float xs[128 * 32];
    __shared__ float wsm[128 * 32];

    const int tid = threadIdx.x;
    const int tx = tid & 15;
    const int ty = tid >> 4;
    const int g  = blockIdx.z;
    const int j0 = blockIdx.y * 128;
    const int row0 = blockIdx.x * 128;

    float acc[8][8];
#pragma unroll
    for (int m = 0; m < 8; ++m)
#pragma unroll
        for (int n = 0; n < 8; ++n) acc[m][n] = 0.f;

    for (int kc = 0; kc < 4; ++kc) {
        __syncthreads();
#pragma unroll
        for (int q = 0; q < 4; ++q) {
            const int f  = tid + 256 * q;
            const int r  = f >> 3;
            const int k4 = f & 7;
            const int rowid = row0 + r;
            const int b   = rowid & 63;
            const int tau = rowid >> 6;
            const float4 xv = *(const float4*)(x + (size_t)(b * T_ + t0 + tau) * IN_
                                                 + g * HG_ + kc * 32 + k4 * 4);
            *(float4*)(xs + r * 32 + ((k4 ^ (r & 7)) << 2)) = xv;
            const float4 wv = *(const float4*)(Wih + (size_t)(g * J3_ + j0 + r) * HG_
                                                   + kc * 32 + k4 * 4);
            *(float4*)(wsm + r * 32 + ((k4 ^ (r & 7)) << 2)) = wv;
        }
        __syncthreads();

#pragma unroll
        for (int k4 = 0; k4 < 8; ++k4) {
            float4 xv[8], wv[8];
#pragma unroll
            for (int m = 0; m < 8; ++m) {
                const int r = ty + 16 * m;
                xv[m] = *(const float4*)(xs + r * 32 + ((k4 ^ (r & 7)) << 2));
            }
#pragma unroll
            for (int n = 0; n < 8; ++n) {
                const int r = tx + 16 * n;
                wv[n] = *(const float4*)(wsm + r * 32 + ((k4 ^ (r & 7)) << 2));
            }
#pragma unroll
            for (int m = 0; m < 8; ++m)
#pragma unroll
                for (int n = 0; n < 8; ++n) {
                    acc[m][n] += xv[m].x * wv[n].x;
                    acc[m][n] += xv[m].y * wv[n].y;
                    acc[m][n] += xv[m].z * wv[n].z;
                    acc[m][n] += xv[m].w * wv[n].w;
                }
        }
    }

#pragma unroll
    for (int m = 0; m < 8; ++m) {
        const int rowid = row0 + ty + 16 * m;
        float* dst = xp + ((size_t)rowid * G_ + g) * J3_ + j0;
#pragma unroll
        for (int n = 0; n < 8; ++n) {
            const int j = tx + 16 * n;
            dst[j] = acc[m][n] + bih[g * J3_ + j0 + j];
        }
    }
}

// ---------------------------------------------------------------------------
// Kernel B (structure D): MFMA recurrence. One 256-thread WG per (b,g).
// y = W_hh (384x128, A-operand, f16 frags PERSISTENT in VGPRs: 24/wave = 96 VGPR)
//     x h (128x1 -> B-operand broadcast to all 16 cols from LDS).
// K accumulated inside the MFMA chain -> no cross-thread reduce.
// mfma_f32_16x16x32_f16 layouts (guide §3, m89-verified D):
//   A: lane l holds A[l&15][(l>>4)*8 + j]   (8 contiguous k)
//   B: lane l holds B[(l>>4)*8 + j][l&15]
//   D: lane l holds D[(l>>4)*4 + r][l&15]
// Per step: 4 ds_read_b128 (h16) + 24 MFMA + masked y write + barrier +
//           gate phase (threads 0..127, all fp32) + barrier.
// ---------------------------------------------------------------------------
__global__ __launch_bounds__(256, 2)
void gru_rec(const float* __restrict__ Whh, const float* __restrict__ bhh,
             const float* __restrict__ xp, float* __restrict__ out,
             float* __restrict__ hstate, int t0, int tc)
{
    const int tid  = threadIdx.x;
    const int lane = tid & 63;
    const int w    = tid >> 6;        // wave 0..3
    const int lr   = lane & 15;       // row-in-tile (A) / col (B,D)
    const int hi   = lane >> 4;       // k/row subgroup 0..3
    const int blk  = blockIdx.x;      // 0..511
    const int b    = blk >> 3;
    const int g    = blk & 7;

    __shared__ _Float16 h16[HG_];
    __shared__ float    hp[J3_];

    // ---- W_hh -> persistent A-fragments: wave w owns M-tiles 6w .. 6w+5 ----
    half8 af[6][4];
#pragma unroll
    for (int i = 0; i < 6; ++i) {
#pragma unroll
        for (int kt = 0; kt < 4; ++kt) {
            const float* p = Whh + (size_t)(g * J3_ + w * 96 + i * 16 + lr) * HG_
                           + kt * 32 + hi * 8;
            const float4 v0 = *(const float4*)(p);
            const float4 v1 = *(const float4*)(p + 4);
            half8 f;
            f[0] = (_Float16)v0.x; f[1] = (_Float16)v0.y;
            f[2] = (_Float16)v0.z; f[3] = (_Float16)v0.w;
            f[4] = (_Float16)v1.x; f[5] = (_Float16)v1.y;
            f[6] = (_Float16)v1.z; f[7] = (_Float16)v1.w;
            af[i][kt] = f;
        }
    }

    float bias0 = 0.f, bias1 = 0.f, bias2 = 0.f, hreg = 0.f;
    if (tid < HG_) {
        bias0 = bhh[g * J3_ +       tid];
        bias1 = bhh[g * J3_ + 128 + tid];
        bias2 = bhh[g * J3_ + 256 + tid];
        hreg  = (t0 == 0) ? 0.f : hstate[(b * G_ + g) * HG_ + tid];
        h16[tid] = (_Float16)hreg;
    }
    __syncthreads();

    const float*  xpb     = xp + ((size_t)b * G_ + g) * J3_;
    const size_t  tstride = (size_t)B_ * G_ * J3_;
    float* outb = out + (size_t)b * T_ * IN_ + (size_t)t0 * IN_ + g * HG_;

    // prefetch xp for tau=0
    float xr = 0.f, xz = 0.f, xn = 0.f;
    if (tid < HG_) { xr = xpb[tid]; xz = xpb[128 + tid]; xn = xpb[256 + tid]; }

    for (int tau = 0; tau < tc; ++tau) {
        // issue next step's xp loads first (hidden under MFMA + gates)
        float nxr = 0.f, nxz = 0.f, nxn = 0.f;
        if (tid < HG_) {
            const int tn = (tau + 1 < tc) ? tau + 1 : tau;
            const float* q = xpb + (size_t)tn * tstride;
            nxr = q[tid]; nxz = q[128 + tid]; nxn = q[256 + tid];
        }

        // B-fragments: h broadcast (uniform addr within each 16-lane group)
        half8 bf[4];
#pragma unroll
        for (int kt = 0; kt < 4; ++kt)
            bf[kt] = *(const half8*)(h16 + kt * 32 + hi * 8);

        // 24 MFMA: 6 M-tiles x 4 K-steps, K accumulated in-register
        f32x4 acc[6];
#pragma unroll
        for (int i = 0; i < 6; ++i) {
            f32x4 a = {0.f, 0.f, 0.f, 0.f};
#pragma unroll
            for (int kt = 0; kt < 4; ++kt)
                a = __builtin_amdgcn_mfma_f32_16x16x32_f16(af[i][kt], bf[kt], a, 0, 0, 0);
            acc[i] = a;
        }

        // col-0 lanes (lr==0) write y rows: 4 consecutive floats per lane
        if (lr == 0) {
#pragma unroll
            for (int i = 0; i < 6; ++i)
                *(f32x4*)(hp + w * 96 + i * 16 + hi * 4) = acc[i];
        }
        __syncthreads();

        // gate phase: threads 0..127 (waves 0-1), all fp32
        if (tid < HG_) {
            const float hr = hp[tid]        + bias0;
            const float hz = hp[128 + tid]  + bias1;
            const float hn = hp[256 + tid]  + bias2;
            const float r = 1.f / (1.f + __expf(-(xr + hr)));
            const float z = 1.f / (1.f + __expf(-(xz + hz)));
            const float pre = xn + r * hn;
            const float e2  = __expf(-2.f * fabsf(pre));
            float th = (1.f - e2) / (1.f + e2);
            th = copysignf(th, pre);
            const float hnew = (1.f - z) * th + z * hreg;
            hreg = hnew;
            h16[tid] = (_Float16)hnew;
            outb[(size_t)tau * IN_ + tid] = hnew;
        }
        __syncthreads();

        xr = nxr; xz = nxz; xn = nxn;
    }

    if (tid < HG_) hstate[(b * G_ + g) * HG_ + tid] = hreg;
}

// ---------------------------------------------------------------------------
extern "C" void kernel_launch(void* const* d_in, const int* in_sizes, int n_in,
                              void* d_out, int out_size, void* d_ws, size_t ws_size,
                              hipStream_t stream) {
    (void)in_sizes; (void)n_in; (void)out_size;
    const float* x   = (const float*)d_in[0];
    const float* Wih = (const float*)d_in[1];
    const float* Whh = (const float*)d_in[2];
    const float* bih = (const float*)d_in[3];
    const float* bhh = (const float*)d_in[4];
    float* out = (float*)d_out;

    // ws layout: [h-state: B*G*128 floats = 256KB][xp chunk buffer]
    const size_t hBytes = (size_t)B_ * G_ * HG_ * sizeof(float);
    float* hstate = (float*)d_ws;
    float* xpbuf  = (float*)((char*)d_ws + hBytes);

    const size_t perT  = (size_t)B_ * G_ * J3_ * sizeof(float);
    const size_t avail = (ws_size > hBytes) ? (ws_size - hBytes) : 0;

    const int cands[8] = {500, 250, 100, 50, 20, 10, 4, 2};
    int tc = 2;
    for (int i = 0; i < 8; ++i) {
        if ((size_t)cands[i] * perT <= avail) { tc = cands[i]; break; }
    }

    for (int t0 = 0; t0 < T_; t0 += tc) {
        dim3 gA(tc * 64 / 128, J3_ / 128, G_);
        gru_xproj<<<gA, 256, 0, stream>>>(x, Wih, bih, xpbuf, t0);
        gru_rec<<<512, 256, 0, stream>>>(Whh, bhh, xpbuf, out, hstate, t0, tc);
    }
}

// Round 4
// 673.616 us; speedup vs baseline: 1.9637x; 1.2569x over previous
//
#include <hip/hip_runtime.h>
#include <math.h>

#define B_   64
#define T_   500
#define IN_  1024
#define G_   8
#define HG_  128
#define J3_  384   // 3*HG

typedef _Float16 half8 __attribute__((ext_vector_type(8)));
typedef float    f32x4 __attribute__((ext_vector_type(4)));

static __device__ __forceinline__ half8 cvt_half8(const float* p) {
    const float4 a = *(const float4*)p;
    const float4 b = *(const float4*)(p + 4);
    half8 h;
    h[0] = (_Float16)a.x; h[1] = (_Float16)a.y; h[2] = (_Float16)a.z; h[3] = (_Float16)a.w;
    h[4] = (_Float16)b.x; h[5] = (_Float16)b.y; h[6] = (_Float16)b.z; h[7] = (_Float16)b.w;
    return h;
}

// ---------------------------------------------------------------------------
// Kernel A (MFMA): xp[(tau*64+b)*G + g][j] = f16( X_g · W_ih[g]^T + b_ih[g] )
// Block: 256 thr = 4 waves (2x2), tile 128 rows x 128 j, K=128 (no K loop).
// A/B frags loaded per-lane directly from global (L1/L2 catch reuse; W is
// L2-resident since g == XCD by grid decode). Output bounced through a
// XOR-swizzled LDS tile for fully coalesced f16 row stores.
// Grid decode: lin = xcd + 8*(jb + 3*q)  ->  g = xcd, j-block jb, row-block q.
// ---------------------------------------------------------------------------
__global__ __launch_bounds__(256, 2)
void gru_xproj(const float* __restrict__ x, const float* __restrict__ Wih,
               const float* __restrict__ bih, _Float16* __restrict__ xp,
               int t0)
{
    __shared__ _Float16 cs[128 * 128];   // 32 KB, XOR-swizzled at 16B granules

    const int lin = blockIdx.x;
    const int g   = lin & 7;             // == XCD (round-robin dispatch)
    const int rem = lin >> 3;
    const int jb  = rem % 3;
    const int q   = rem / 3;             // row-block
    const int j0  = jb * 128;
    const int row0 = q * 128;            // rowid = tau*64 + b

    const int tid  = threadIdx.x;
    const int lane = tid & 63;
    const int w    = tid >> 6;
    const int wm   = w >> 1, wn = w & 1;
    const int lr   = lane & 15, hi = lane >> 4;

    // per-lane global bases
    const float* xbase[4];
#pragma unroll
    for (int mi = 0; mi < 4; ++mi) {
        const int row = row0 + wm * 64 + mi * 16 + lr;
        const int b   = row & 63;
        const int tau = row >> 6;
        xbase[mi] = x + ((size_t)b * T_ + t0 + tau) * IN_ + g * HG_;
    }
    const float* wbase[4];
#pragma unroll
    for (int ni = 0; ni < 4; ++ni)
        wbase[ni] = Wih + (size_t)(g * J3_ + j0 + wn * 64 + ni * 16 + lr) * HG_;

    f32x4 acc[4][4];
#pragma unroll
    for (int mi = 0; mi < 4; ++mi)
#pragma unroll
        for (int ni = 0; ni < 4; ++ni) acc[mi][ni] = (f32x4){0.f, 0.f, 0.f, 0.f};

#pragma unroll
    for (int kt = 0; kt < 4; ++kt) {
        half8 af[4], bf[4];
#pragma unroll
        for (int mi = 0; mi < 4; ++mi) af[mi] = cvt_half8(xbase[mi] + kt * 32 + hi * 8);
#pragma unroll
        for (int ni = 0; ni < 4; ++ni) bf[ni] = cvt_half8(wbase[ni] + kt * 32 + hi * 8);
#pragma unroll
        for (int mi = 0; mi < 4; ++mi)
#pragma unroll
            for (int ni = 0; ni < 4; ++ni)
                acc[mi][ni] = __builtin_amdgcn_mfma_f32_16x16x32_f16(af[mi], bf[ni], acc[mi][ni], 0, 0, 0);
    }

    // bias + swizzled LDS write (D layout: lane holds D[hi*4+r][lr])
    float bias[4];
#pragma unroll
    for (int ni = 0; ni < 4; ++ni) bias[ni] = bih[g * J3_ + j0 + wn * 64 + ni * 16 + lr];

#pragma unroll
    for (int mi = 0; mi < 4; ++mi)
#pragma unroll
        for (int ni = 0; ni < 4; ++ni)
#pragma unroll
            for (int r = 0; r < 4; ++r) {
                const int row  = wm * 64 + mi * 16 + hi * 4 + r;
                const int colb = (wn * 64 + ni * 16 + lr) * 2;
                const int addr = row * 256 + (colb ^ ((row & 7) << 4));
                *(_Float16*)((char*)cs + addr) = (_Float16)(acc[mi][ni][r] + bias[ni]);
            }
    __syncthreads();

    // coalesced stores: 16 lanes cover one full 256B row
#pragma unroll
    for (int s = 0; s < 8; ++s) {
        const int u   = s * 256 + tid;       // 2048 16B-chunks
        const int row = u >> 4;
        const int c16 = u & 15;
        const int addr = row * 256 + ((c16 * 16) ^ ((row & 7) << 4));
        const half8 v = *(const half8*)((const char*)cs + addr);
        *(half8*)(xp + ((size_t)(row0 + row) * G_ + g) * J3_ + j0 + c16 * 8) = v;
    }
}

// ---------------------------------------------------------------------------
// Kernel B (structure E): 256 blocks (b-pair x g), 512 thr = 8 waves.
// Two sequences share each MFMA: B-operand column parity = sequence
// (lane reads h16[lr&1]); D col 0/1 -> y for seq 0/1. Wave w owns y-rows
// [48w, 48w+48) as 3 M-tiles; W_hh frags persistent (48 VGPR/wave).
// Per step: bf ds_read -> 12 MFMA -> y to LDS (lr<2) -> barrier ->
//           gates on threads<256 (1 j each, fp32) -> barrier.
// ---------------------------------------------------------------------------
__global__ __launch_bounds__(512, 2)
void gru_rec(const float* __restrict__ Whh, const float* __restrict__ bhh,
             const _Float16* __restrict__ xp, float* __restrict__ out,
             float* __restrict__ hstate, int t0, int tc)
{
    const int tid  = threadIdx.x;
    const int lane = tid & 63;
    const int w    = tid >> 6;        // 0..7
    const int lr   = lane & 15, hi = lane >> 4;
    const int blk  = blockIdx.x;      // 0..255
    const int g    = blk & 7;         // == XCD
    const int bp   = blk >> 3;        // b-pair 0..31

    __shared__ _Float16 h16[2 * HG_];
    __shared__ float    hp[2 * J3_];

    // persistent A-frags: wave w -> W_hh rows 48w..48w+47 (3 tiles x 4 K-steps)
    half8 af[3][4];
#pragma unroll
    for (int i = 0; i < 3; ++i)
#pragma unroll
        for (int kt = 0; kt < 4; ++kt)
            af[i][kt] = cvt_half8(Whh + (size_t)(g * J3_ + w * 48 + i * 16 + lr) * HG_
                                      + kt * 32 + hi * 8);

    // gate-thread state (threads 0..255): sq = tid>>7, j = tid&127
    const int sq = tid >> 7, j = tid & 127;
    const int b  = bp * 2 + sq;
    float hreg = 0.f, br = 0.f, bz = 0.f, bn = 0.f;
    if (tid < 256) {
        br = bhh[g * J3_ + j];
        bz = bhh[g * J3_ + 128 + j];
        bn = bhh[g * J3_ + 256 + j];
        hreg = (t0 == 0) ? 0.f : hstate[(b * G_ + g) * HG_ + j];
        h16[sq * HG_ + j] = (_Float16)hreg;
    }
    __syncthreads();

    const size_t TS = (size_t)64 * G_ * J3_;                       // per-tau stride
    const _Float16* xpbg = xp + ((size_t)b * G_ + g) * J3_;        // + tau*TS
    float* outbg = out + (size_t)b * T_ * IN_ + (size_t)t0 * IN_ + g * HG_;

    float xr = 0.f, xz = 0.f, xn = 0.f;
    if (tid < 256) {
        xr = (float)xpbg[j]; xz = (float)xpbg[128 + j]; xn = (float)xpbg[256 + j];
    }

    for (int tau = 0; tau < tc; ++tau) {
        // prefetch next step's xp (consumed next iteration)
        float nxr = 0.f, nxz = 0.f, nxn = 0.f;
        if (tid < 256) {
            const int tn = (tau + 1 < tc) ? tau + 1 : tau;
            const _Float16* p = xpbg + (size_t)tn * TS;
            nxr = (float)p[j]; nxz = (float)p[128 + j]; nxn = (float)p[256 + j];
        }

        // B-frags: column parity = sequence
        half8 bf[4];
        const _Float16* hsrc = h16 + (lr & 1) * HG_;
#pragma unroll
        for (int kt = 0; kt < 4; ++kt)
            bf[kt] = *(const half8*)(hsrc + kt * 32 + hi * 8);

        f32x4 acc[3];
#pragma unroll
        for (int i = 0; i < 3; ++i) {
            f32x4 a = (f32x4){0.f, 0.f, 0.f, 0.f};
#pragma unroll
            for (int kt = 0; kt < 4; ++kt)
                a = __builtin_amdgcn_mfma_f32_16x16x32_f16(af[i][kt], bf[kt], a, 0, 0, 0);
            acc[i] = a;
        }

        if (lr < 2) {
#pragma unroll
            for (int i = 0; i < 3; ++i)
                *(f32x4*)(hp + lr * J3_ + w * 48 + i * 16 + hi * 4) = acc[i];
        }
        __syncthreads();

        if (tid < 256) {
            const float hr = hp[sq * J3_ + j]       + br;
            const float hz = hp[sq * J3_ + 128 + j] + bz;
            const float hn = hp[sq * J3_ + 256 + j] + bn;
            const float r = 1.f / (1.f + __expf(-(xr + hr)));
            const float z = 1.f / (1.f + __expf(-(xz + hz)));
            const float pre = xn + r * hn;
            const float e2  = __expf(-2.f * fabsf(pre));
            float th = (1.f - e2) / (1.f + e2);
            th = copysignf(th, pre);
            const float hnew = (1.f - z) * th + z * hreg;
            hreg = hnew;
            h16[sq * HG_ + j] = (_Float16)hnew;
            outbg[(size_t)tau * IN_ + j] = hnew;
        }
        __syncthreads();

        xr = nxr; xz = nxz; xn = nxn;
    }

    if (tid < 256) hstate[(b * G_ + g) * HG_ + j] = hreg;
}

// ---------------------------------------------------------------------------
extern "C" void kernel_launch(void* const* d_in, const int* in_sizes, int n_in,
                              void* d_out, int out_size, void* d_ws, size_t ws_size,
                              hipStream_t stream) {
    (void)in_sizes; (void)n_in; (void)out_size;
    const float* x   = (const float*)d_in[0];
    const float* Wih = (const float*)d_in[1];
    const float* Whh = (const float*)d_in[2];
    const float* bih = (const float*)d_in[3];
    const float* bhh = (const float*)d_in[4];
    float* out = (float*)d_out;

    // ws layout: [h-state: B*G*128 f32 = 256KB][xp chunk buffer, f16]
    const size_t hBytes = (size_t)B_ * G_ * HG_ * sizeof(float);
    float*     hstate = (float*)d_ws;
    _Float16*  xpbuf  = (_Float16*)((char*)d_ws + hBytes);

    const size_t perT  = (size_t)B_ * G_ * J3_ * sizeof(_Float16);  // 393216 B
    const size_t avail = (ws_size > hBytes) ? (ws_size - hBytes) : 0;

    const int cands[8] = {500, 250, 100, 50, 20, 10, 4, 2};
    int tc = 2;
    for (int i = 0; i < 8; ++i) {
        if ((size_t)cands[i] * perT <= avail) { tc = cands[i]; break; }
    }

    for (int t0 = 0; t0 < T_; t0 += tc) {
        const int RB = tc * 64 / 128;           // row-blocks of 128 (tau,b) rows
        gru_xproj<<<24 * RB, 256, 0, stream>>>(x, Wih, bih, xpbuf, t0);
        gru_rec<<<256, 512, 0, stream>>>(Whh, bhh, xpbuf, out, hstate, t0, tc);
    }
}